// Round 12
// baseline (83.981 us; speedup 1.0000x reference)
//
#include <hip/hip_runtime.h>
#include <hip/hip_bf16.h>
#include <math.h>

#define NTOK 4096
#define CDIM 256
#define NH   8
#define HD   32
// 32^-0.5 * log2(e): QK^T scale with exp->exp2 fold
#define QSCALE 0.2550565445517151f
#define ATTN_REP 4

typedef __attribute__((ext_vector_type(8))) short bf16x8;
typedef __attribute__((ext_vector_type(4))) short short4v;
typedef __attribute__((ext_vector_type(4))) float f32x4;

__device__ inline short f2b(float f) {
  union { __hip_bfloat16 h; short s; } u;
  u.h = __float2bfloat16(f);
  return u.s;
}
__device__ inline short4v pack4(f32x4 v) {
  short4v o; o[0] = f2b(v[0]); o[1] = f2b(v[1]); o[2] = f2b(v[2]); o[3] = f2b(v[3]);
  return o;
}

// ---------------- prep: bf16 conversions + weight transposes ----------------
__global__ __launch_bounds__(256) void prep_kernel(
    const float* __restrict__ qkv, const float* __restrict__ qpos,
    const float* __restrict__ Wq, const float* __restrict__ Wkv,
    const float* __restrict__ Wp,
    short* __restrict__ Xq, short* __restrict__ X,
    short* __restrict__ WT, short* __restrict__ WpT)
{
  const int b = blockIdx.x, t = threadIdx.x;
  if (b < 1024) {
    const int i4 = (b * 256 + t) * 4;
    float4 a = *(const float4*)(qkv + i4);
    float4 p = *(const float4*)(qpos + i4);
    short4v xo, qo;
    xo[0] = f2b(a.x); xo[1] = f2b(a.y); xo[2] = f2b(a.z); xo[3] = f2b(a.w);
    qo[0] = f2b(a.x + p.x); qo[1] = f2b(a.y + p.y); qo[2] = f2b(a.z + p.z); qo[3] = f2b(a.w + p.w);
    *(short4v*)(X + i4)  = xo;
    *(short4v*)(Xq + i4) = qo;
  } else {
    const int gid = (b - 1024) * 256 + t;   // 0..65535
    const int c  = gid & 1023;
    const int k4 = (gid >> 10) * 4;
    short4v o;
    if (c < 768) {
      #pragma unroll
      for (int j = 0; j < 4; ++j) {
        int k = k4 + j;
        float v = (c < 256) ? Wq[(size_t)k * 256 + c] * QSCALE
                            : Wkv[(size_t)k * 512 + (c - 256)];
        o[j] = f2b(v);
      }
      *(short4v*)(WT + (size_t)c * 256 + k4) = o;
    } else {
      const int cc = c - 768;
      #pragma unroll
      for (int j = 0; j < 4; ++j) o[j] = f2b(Wp[(size_t)(k4 + j) * 256 + cc]);
      *(short4v*)(WpT + (size_t)cc * 256 + k4) = o;
    }
  }
}

// ---------------- fused QKV projection (MFMA, 64x64 tiles) ----------------
// bx 0..3: q -> qb[n][c] (swapped); bx 4..7: k -> khp[h][tile][slot][d]
// (per-tile key-permuted); bx 8..11: v -> vblk[h][tile][d][k] (tile-blocked)
__global__ __launch_bounds__(256) void gemm_qkv(
    const short* __restrict__ Xq, const short* __restrict__ X,
    const short* __restrict__ WT,
    short* __restrict__ qb, short* __restrict__ khp, short* __restrict__ vblk)
{
  __shared__ short Al[64][40];
  __shared__ short Wl[64][40];
  const int bx = blockIdx.x;
  const int n0 = blockIdx.y * 64;
  const int c0 = bx * 64;                   // row range in WT [0,768)
  const int tid = threadIdx.x;
  const int w = tid >> 6, l = tid & 63, lg = l >> 4, lr = l & 15;
  const int wc = w & 1, wn = w >> 1;
  const short* A = (bx < 4) ? Xq : X;

  f32x4 acc[2][2];
  #pragma unroll
  for (int i = 0; i < 2; ++i)
    #pragma unroll
    for (int j = 0; j < 2; ++j) acc[i][j] = (f32x4){0.f, 0.f, 0.f, 0.f};

  for (int kt = 0; kt < 256; kt += 32) {
    __syncthreads();
    {
      int row = tid >> 2, seg = tid & 3;
      *(bf16x8*)&Al[row][seg * 8] = *(const bf16x8*)(A  + (size_t)(n0 + row) * 256 + kt + seg * 8);
      *(bf16x8*)&Wl[row][seg * 8] = *(const bf16x8*)(WT + (size_t)(c0 + row) * 256 + kt + seg * 8);
    }
    __syncthreads();
    bf16x8 wf[2], xf[2];
    #pragma unroll
    for (int ci = 0; ci < 2; ++ci) wf[ci] = *(bf16x8*)&Wl[wc * 32 + ci * 16 + lr][lg * 8];
    #pragma unroll
    for (int ni = 0; ni < 2; ++ni) xf[ni] = *(bf16x8*)&Al[wn * 32 + ni * 16 + lr][lg * 8];
    if (bx < 8) {
      #pragma unroll
      for (int ci = 0; ci < 2; ++ci)
        #pragma unroll
        for (int ni = 0; ni < 2; ++ni)
          acc[ci][ni] = __builtin_amdgcn_mfma_f32_16x16x32_bf16(wf[ci], xf[ni], acc[ci][ni], 0, 0, 0);
    } else {
      #pragma unroll
      for (int ci = 0; ci < 2; ++ci)
        #pragma unroll
        for (int ni = 0; ni < 2; ++ni)
          acc[ci][ni] = __builtin_amdgcn_mfma_f32_16x16x32_bf16(xf[ni], wf[ci], acc[ci][ni], 0, 0, 0);
    }
  }

  if (bx < 4) {
    const int cl0 = bx * 64;
    #pragma unroll
    for (int ci = 0; ci < 2; ++ci)
      #pragma unroll
      for (int ni = 0; ni < 2; ++ni) {
        int c = cl0 + wc * 32 + ci * 16 + lg * 4;
        int n = n0 + wn * 32 + ni * 16 + lr;
        *(short4v*)(qb + (size_t)n * 256 + c) = pack4(acc[ci][ni]);
      }
  } else if (bx < 8) {
    // k: khp[h][tile][slot][d], slot = ((k>>2)&1)*16 + (k>>3)*4 + (k&3)
    const int cl0 = (bx - 4) * 64;
    #pragma unroll
    for (int ci = 0; ci < 2; ++ci)
      #pragma unroll
      for (int ni = 0; ni < 2; ++ni) {
        int c = cl0 + wc * 32 + ci * 16 + lg * 4;
        int n = n0 + wn * 32 + ni * 16 + lr;
        int hh = c >> 5, d = c & 31;
        int tt = n >> 5, k = n & 31;
        int s = ((k >> 2) & 1) * 16 + (k >> 3) * 4 + (k & 3);
        *(short4v*)(khp + (((size_t)hh * 128 + tt) * 32 + s) * 32 + d) = pack4(acc[ci][ni]);
      }
  } else {
    // v: vblk[h][tile][d][k]
    const int cv0 = (bx - 8) * 64;
    #pragma unroll
    for (int ci = 0; ci < 2; ++ci)
      #pragma unroll
      for (int ni = 0; ni < 2; ++ni) {
        int c = cv0 + wc * 32 + ci * 16 + lr;
        int n = n0 + wn * 32 + ni * 16 + lg * 4;
        int hh = c >> 5, d = c & 31;
        int tt = n >> 5, k = n & 31;
        *(short4v*)(vblk + (((size_t)hh * 128 + tt) * 32 + d) * 32 + k) = pack4(acc[ci][ni]);
      }
  }
}

// ---------------- attn10: attn7 + exp2-fold, REP'd x4 for diagnosis ----------------
// The rep loop multiplies acc and L by REP identically; o = acc/L is invariant.
// Inline-asm pointer launder per rep defeats cross-rep load CSE.
__global__ __launch_bounds__(256) void attn10(
    const short* __restrict__ qb, const short* __restrict__ khp,
    const short* __restrict__ vblk, const int* __restrict__ cu,
    short* __restrict__ featb)
{
  __shared__ float red[4][64][18];
  const int tid = threadIdx.x;
  const int w = tid >> 6, l = tid & 63, lg = l >> 4, lr = l & 15;
  const int bid = blockIdx.x;                       // 1024 blocks (8 | 1024)
  const int lid = ((bid & 7) << 7) | (bid >> 3);    // bijective XCD swizzle
  const int h = lid & 7, t32 = lid >> 3;
  const int n0 = t32 * 32;

  int cs[9];
  #pragma unroll
  for (int i = 0; i < 9; ++i) cs[i] = cu[i];

  const int qn0 = n0 + lr, qn1 = n0 + 16 + lr;
  int g0 = 0, g1 = 0, sg0 = 0, sgL = 0;
  #pragma unroll
  for (int j = 1; j <= 8; ++j) {
    g0  += (cs[j] <= qn0);
    g1  += (cs[j] <= qn1);
    sg0 += (cs[j] <= n0);
    sgL += (cs[j] <= n0 + 31);
  }
  const int kbeg0 = cs[g0], kend0 = cs[g0 + 1];
  const int kbeg1 = cs[g1], kend1 = cs[g1 + 1];
  const bool oneSeg = (sg0 == sgL);
  const int kbB = cs[sg0], keB = cs[sgL + 1];
  const int lo = kbB & ~31;
  const int hi = keB;
  const int t0 = lo >> 5;
  const int nT = (hi - lo + 31) >> 5;
  const int qT = (nT + 3) >> 2;
  const int it0 = w * qT;
  const int it1 = (it0 + qT < nT) ? (it0 + qT) : nT;

  const bf16x8 qf0 = *(const bf16x8*)(qb + (size_t)qn0 * 256 + h * 32 + lg * 8);
  const bf16x8 qf1 = *(const bf16x8*)(qb + (size_t)qn1 * 256 + h * 32 + lg * 8);
  const short* kL = khp  + (size_t)h * 131072 + lr * 32 + lg * 8;
  const short* vL = vblk + (size_t)h * 131072 + lr * 32 + lg * 8;

  f32x4 acc00 = {0.f,0.f,0.f,0.f}, acc01 = {0.f,0.f,0.f,0.f};
  f32x4 acc10 = {0.f,0.f,0.f,0.f}, acc11 = {0.f,0.f,0.f,0.f};
  float Lp0 = 0.f, Lp1 = 0.f;
  const f32x4 z4 = {0.f, 0.f, 0.f, 0.f};

  for (int rep = 0; rep < ATTN_REP; ++rep) {
    const short* kLr = kL;
    const short* vLr = vL;
    // launder pointers so loads cannot be CSE'd across reps
    asm volatile("" : "+v"(kLr), "+v"(vLr));
    if (it0 < it1) {
      const short* kp = kLr + (size_t)(t0 + it0) * 1024;
      const short* vp = vLr + (size_t)(t0 + it0) * 1024;
      bf16x8 ka = *(const bf16x8*)(kp);
      bf16x8 kc = *(const bf16x8*)(kp + 512);
      bf16x8 va = *(const bf16x8*)(vp);
      bf16x8 vb = *(const bf16x8*)(vp + 512);
      for (int it = it0; it < it1; ++it) {
        const int itn = (it + 1 < it1) ? (it + 1) : it;
        const short* kpn = kLr + (size_t)(t0 + itn) * 1024;
        const short* vpn = vLr + (size_t)(t0 + itn) * 1024;
        bf16x8 kna = *(const bf16x8*)(kpn);
        bf16x8 knc = *(const bf16x8*)(kpn + 512);
        bf16x8 vna = *(const bf16x8*)(vpn);
        bf16x8 vnb = *(const bf16x8*)(vpn + 512);

        f32x4 s00 = __builtin_amdgcn_mfma_f32_16x16x32_bf16(ka, qf0, z4, 0, 0, 0);
        f32x4 s01 = __builtin_amdgcn_mfma_f32_16x16x32_bf16(kc, qf0, z4, 0, 0, 0);
        f32x4 s10 = __builtin_amdgcn_mfma_f32_16x16x32_bf16(ka, qf1, z4, 0, 0, 0);
        f32x4 s11 = __builtin_amdgcn_mfma_f32_16x16x32_bf16(kc, qf1, z4, 0, 0, 0);

        const int kt0 = (t0 + it) * 32;
        bf16x8 pf0, pf1;
        if (oneSeg & (kt0 >= kbB) & (kt0 + 32 <= keB)) {
          #pragma unroll
          for (int r = 0; r < 4; ++r) {
            float p00 = exp2f(s00[r]), p01 = exp2f(s01[r]);
            float p10 = exp2f(s10[r]), p11 = exp2f(s11[r]);
            Lp0 += p00 + p01; Lp1 += p10 + p11;
            pf0[r] = f2b(p00); pf0[4 + r] = f2b(p01);
            pf1[r] = f2b(p10); pf1[4 + r] = f2b(p11);
          }
        } else {
          const int kgb = kt0 + lg * 8;
          #pragma unroll
          for (int r = 0; r < 4; ++r) {
            int k0 = kgb + r, k1 = kgb + 4 + r;
            bool a00 = (k0 >= kbeg0) & (k0 < kend0);
            bool a01 = (k1 >= kbeg0) & (k1 < kend0);
            bool a10 = (k0 >= kbeg1) & (k0 < kend1);
            bool a11 = (k1 >= kbeg1) & (k1 < kend1);
            float p00 = a00 ? exp2f(s00[r]) : 0.f;
            float p01 = a01 ? exp2f(s01[r]) : 0.f;
            float p10 = a10 ? exp2f(s10[r]) : 0.f;
            float p11 = a11 ? exp2f(s11[r]) : 0.f;
            Lp0 += p00 + p01; Lp1 += p10 + p11;
            pf0[r] = f2b(p00); pf0[4 + r] = f2b(p01);
            pf1[r] = f2b(p10); pf1[4 + r] = f2b(p11);
          }
        }
        acc00 = __builtin_amdgcn_mfma_f32_16x16x32_bf16(pf0, va, acc00, 0, 0, 0);
        acc01 = __builtin_amdgcn_mfma_f32_16x16x32_bf16(pf0, vb, acc01, 0, 0, 0);
        acc10 = __builtin_amdgcn_mfma_f32_16x16x32_bf16(pf1, va, acc10, 0, 0, 0);
        acc11 = __builtin_amdgcn_mfma_f32_16x16x32_bf16(pf1, vb, acc11, 0, 0, 0);

        ka = kna; kc = knc; va = vna; vb = vnb;
      }
    }
  }

  // merge the 4 key-splits: pure sum (fixed-max softmax); rep factor cancels
  #pragma unroll
  for (int r = 0; r < 4; ++r) {
    red[w][l][r]      = acc00[r];
    red[w][l][4 + r]  = acc01[r];
    red[w][l][8 + r]  = acc10[r];
    red[w][l][12 + r] = acc11[r];
  }
  red[w][l][16] = Lp0;
  red[w][l][17] = Lp1;
  __syncthreads();
  if (w == 0) {
    float a00[4] = {0,0,0,0}, a01[4] = {0,0,0,0};
    float a10[4] = {0,0,0,0}, a11[4] = {0,0,0,0};
    float Ls0 = 0.f, Ls1 = 0.f;
    #pragma unroll
    for (int wv = 0; wv < 4; ++wv) {
      #pragma unroll
      for (int r = 0; r < 4; ++r) {
        a00[r] += red[wv][l][r];      a01[r] += red[wv][l][4 + r];
        a10[r] += red[wv][l][8 + r];  a11[r] += red[wv][l][12 + r];
      }
      Ls0 += red[wv][l][16];
      Ls1 += red[wv][l][17];
    }
    Ls0 += __shfl_xor(Ls0, 16); Ls0 += __shfl_xor(Ls0, 32);
    Ls1 += __shfl_xor(Ls1, 16); Ls1 += __shfl_xor(Ls1, 32);
    float inv0 = 1.f / Ls0, inv1 = 1.f / Ls1;
    #pragma unroll
    for (int r = 0; r < 4; ++r) {
      float i0 = __shfl(inv0, lg * 4 + r);
      float i1 = __shfl(inv1, lg * 4 + r);
      int na = n0 + lg * 4 + r;
      int nb = n0 + 16 + lg * 4 + r;
      featb[(size_t)na * 256 + h * 32 + lr]      = f2b(a00[r] * i0);
      featb[(size_t)na * 256 + h * 32 + 16 + lr] = f2b(a01[r] * i0);
      featb[(size_t)nb * 256 + h * 32 + lr]      = f2b(a10[r] * i1);
      featb[(size_t)nb * 256 + h * 32 + 16 + lr] = f2b(a11[r] * i1);
    }
  }
}

// ---------------- output projection (MFMA, 64x64 tiles, swapped) + bias ----------------
__global__ __launch_bounds__(256) void gemm_out(
    const short* __restrict__ Fb, const short* __restrict__ WpT,
    const float* __restrict__ bias, float* __restrict__ out)
{
  __shared__ short Al[64][40];
  __shared__ short Wl[64][40];
  const int c0 = blockIdx.x * 64;
  const int n0 = blockIdx.y * 64;
  const int tid = threadIdx.x;
  const int w = tid >> 6, l = tid & 63, lg = l >> 4, lr = l & 15;
  const int wc = w & 1, wn = w >> 1;

  f32x4 acc[2][2];
  #pragma unroll
  for (int i = 0; i < 2; ++i)
    #pragma unroll
    for (int j = 0; j < 2; ++j) acc[i][j] = (f32x4){0.f, 0.f, 0.f, 0.f};

  for (int kt = 0; kt < 256; kt += 32) {
    __syncthreads();
    {
      int row = tid >> 2, seg = tid & 3;
      *(bf16x8*)&Al[row][seg * 8] = *(const bf16x8*)(Fb  + (size_t)(n0 + row) * 256 + kt + seg * 8);
      *(bf16x8*)&Wl[row][seg * 8] = *(const bf16x8*)(WpT + (size_t)(c0 + row) * 256 + kt + seg * 8);
    }
    __syncthreads();
    bf16x8 wf[2], xf[2];
    #pragma unroll
    for (int ci = 0; ci < 2; ++ci) wf[ci] = *(bf16x8*)&Wl[wc * 32 + ci * 16 + lr][lg * 8];
    #pragma unroll
    for (int ni = 0; ni < 2; ++ni) xf[ni] = *(bf16x8*)&Al[wn * 32 + ni * 16 + lr][lg * 8];
    #pragma unroll
    for (int ci = 0; ci < 2; ++ci)
      #pragma unroll
      for (int ni = 0; ni < 2; ++ni)
        acc[ci][ni] = __builtin_amdgcn_mfma_f32_16x16x32_bf16(wf[ci], xf[ni], acc[ci][ni], 0, 0, 0);
  }

  #pragma unroll
  for (int ci = 0; ci < 2; ++ci)
    #pragma unroll
    for (int ni = 0; ni < 2; ++ni) {
      int c = c0 + wc * 32 + ci * 16 + lg * 4;
      int n = n0 + wn * 32 + ni * 16 + lr;
      f32x4 bv = *(const f32x4*)(bias + c);
      f32x4 o = acc[ci][ni] + bv;
      *(f32x4*)(out + (size_t)n * 256 + c) = o;
    }
}

extern "C" void kernel_launch(void* const* d_in, const int* in_sizes, int n_in,
                              void* d_out, int out_size, void* d_ws, size_t ws_size,
                              hipStream_t stream) {
  (void)in_sizes; (void)n_in; (void)out_size; (void)ws_size;
  const float* qkv   = (const float*)d_in[0];
  const float* q_pos = (const float*)d_in[1];
  const int*   cu    = (const int*)d_in[2];
  const float* Wq    = (const float*)d_in[4];
  const float* Wkv   = (const float*)d_in[5];
  const float* Wproj = (const float*)d_in[6];
  const float* bproj = (const float*)d_in[7];
  float* out = (float*)d_out;

  const size_t M = (size_t)NTOK * CDIM;   // 1048576
  short* S    = (short*)d_ws;
  short* Xq   = S;
  short* X    = S + M;
  short* qb   = S + 2 * M;
  short* khp  = S + 3 * M;
  short* vblk = S + 4 * M;
  short* Fb   = S + 5 * M;
  short* WT   = S + 6 * M;
  short* WpT  = WT + 768 * 256;

  prep_kernel<<<1280, 256, 0, stream>>>(qkv, q_pos, Wq, Wkv, Wproj, Xq, X, WT, WpT);
  gemm_qkv<<<dim3(12, 64), 256, 0, stream>>>(Xq, X, WT, qb, khp, vblk);
  attn10<<<1024, 256, 0, stream>>>(qb, khp, vblk, cu, Fb);
  gemm_out<<<dim3(4, 64), 256, 0, stream>>>(Fb, WpT, bproj, out);
}

// Round 13
// 54.225 us; speedup vs baseline: 1.5487x; 1.5487x over previous
//
#include <hip/hip_runtime.h>
#include <hip/hip_bf16.h>
#include <math.h>

#define NTOK 4096
#define CDIM 256
#define NH   8
#define HD   32
// 32^-0.5 * log2(e): QK^T scale with exp->exp2 fold
#define QSCALE 0.2550565445517151f

typedef __attribute__((ext_vector_type(8))) short bf16x8;
typedef __attribute__((ext_vector_type(4))) short short4v;
typedef __attribute__((ext_vector_type(4))) float f32x4;

__device__ inline short f2b(float f) {
  union { __hip_bfloat16 h; short s; } u;
  u.h = __float2bfloat16(f);
  return u.s;
}
__device__ inline short4v pack4(f32x4 v) {
  short4v o; o[0] = f2b(v[0]); o[1] = f2b(v[1]); o[2] = f2b(v[2]); o[3] = f2b(v[3]);
  return o;
}

// ---------------- prep: bf16 conversions + weight transposes ----------------
__global__ __launch_bounds__(256) void prep_kernel(
    const float* __restrict__ qkv, const float* __restrict__ qpos,
    const float* __restrict__ Wq, const float* __restrict__ Wkv,
    const float* __restrict__ Wp,
    short* __restrict__ Xq, short* __restrict__ X,
    short* __restrict__ WT, short* __restrict__ WpT)
{
  const int b = blockIdx.x, t = threadIdx.x;
  if (b < 1024) {
    const int i4 = (b * 256 + t) * 4;
    float4 a = *(const float4*)(qkv + i4);
    float4 p = *(const float4*)(qpos + i4);
    short4v xo, qo;
    xo[0] = f2b(a.x); xo[1] = f2b(a.y); xo[2] = f2b(a.z); xo[3] = f2b(a.w);
    qo[0] = f2b(a.x + p.x); qo[1] = f2b(a.y + p.y); qo[2] = f2b(a.z + p.z); qo[3] = f2b(a.w + p.w);
    *(short4v*)(X + i4)  = xo;
    *(short4v*)(Xq + i4) = qo;
  } else {
    const int gid = (b - 1024) * 256 + t;   // 0..65535
    const int c  = gid & 1023;
    const int k4 = (gid >> 10) * 4;
    short4v o;
    if (c < 768) {
      #pragma unroll
      for (int j = 0; j < 4; ++j) {
        int k = k4 + j;
        float v = (c < 256) ? Wq[(size_t)k * 256 + c] * QSCALE
                            : Wkv[(size_t)k * 512 + (c - 256)];
        o[j] = f2b(v);
      }
      *(short4v*)(WT + (size_t)c * 256 + k4) = o;
    } else {
      const int cc = c - 768;
      #pragma unroll
      for (int j = 0; j < 4; ++j) o[j] = f2b(Wp[(size_t)(k4 + j) * 256 + cc]);
      *(short4v*)(WpT + (size_t)cc * 256 + k4) = o;
    }
  }
}

// ---------------- fused QKV projection (MFMA, 64x64 tiles) ----------------
// bx 0..3: q -> qb[n][c] (swapped); bx 4..7: k -> khp[h][tile][slot][d]
// (per-tile key-permuted); bx 8..11: v -> vblk[h][tile][d][k] (tile-blocked)
__global__ __launch_bounds__(256) void gemm_qkv(
    const short* __restrict__ Xq, const short* __restrict__ X,
    const short* __restrict__ WT,
    short* __restrict__ qb, short* __restrict__ khp, short* __restrict__ vblk)
{
  __shared__ short Al[64][40];
  __shared__ short Wl[64][40];
  const int bx = blockIdx.x;
  const int n0 = blockIdx.y * 64;
  const int c0 = bx * 64;                   // row range in WT [0,768)
  const int tid = threadIdx.x;
  const int w = tid >> 6, l = tid & 63, lg = l >> 4, lr = l & 15;
  const int wc = w & 1, wn = w >> 1;
  const short* A = (bx < 4) ? Xq : X;

  f32x4 acc[2][2];
  #pragma unroll
  for (int i = 0; i < 2; ++i)
    #pragma unroll
    for (int j = 0; j < 2; ++j) acc[i][j] = (f32x4){0.f, 0.f, 0.f, 0.f};

  for (int kt = 0; kt < 256; kt += 32) {
    __syncthreads();
    {
      int row = tid >> 2, seg = tid & 3;
      *(bf16x8*)&Al[row][seg * 8] = *(const bf16x8*)(A  + (size_t)(n0 + row) * 256 + kt + seg * 8);
      *(bf16x8*)&Wl[row][seg * 8] = *(const bf16x8*)(WT + (size_t)(c0 + row) * 256 + kt + seg * 8);
    }
    __syncthreads();
    bf16x8 wf[2], xf[2];
    #pragma unroll
    for (int ci = 0; ci < 2; ++ci) wf[ci] = *(bf16x8*)&Wl[wc * 32 + ci * 16 + lr][lg * 8];
    #pragma unroll
    for (int ni = 0; ni < 2; ++ni) xf[ni] = *(bf16x8*)&Al[wn * 32 + ni * 16 + lr][lg * 8];
    if (bx < 8) {
      #pragma unroll
      for (int ci = 0; ci < 2; ++ci)
        #pragma unroll
        for (int ni = 0; ni < 2; ++ni)
          acc[ci][ni] = __builtin_amdgcn_mfma_f32_16x16x32_bf16(wf[ci], xf[ni], acc[ci][ni], 0, 0, 0);
    } else {
      #pragma unroll
      for (int ci = 0; ci < 2; ++ci)
        #pragma unroll
        for (int ni = 0; ni < 2; ++ni)
          acc[ci][ni] = __builtin_amdgcn_mfma_f32_16x16x32_bf16(xf[ni], wf[ci], acc[ci][ni], 0, 0, 0);
    }
  }

  if (bx < 4) {
    const int cl0 = bx * 64;
    #pragma unroll
    for (int ci = 0; ci < 2; ++ci)
      #pragma unroll
      for (int ni = 0; ni < 2; ++ni) {
        int c = cl0 + wc * 32 + ci * 16 + lg * 4;
        int n = n0 + wn * 32 + ni * 16 + lr;
        *(short4v*)(qb + (size_t)n * 256 + c) = pack4(acc[ci][ni]);
      }
  } else if (bx < 8) {
    // k: khp[h][tile][slot][d], slot = ((k>>2)&1)*16 + (k>>3)*4 + (k&3)
    const int cl0 = (bx - 4) * 64;
    #pragma unroll
    for (int ci = 0; ci < 2; ++ci)
      #pragma unroll
      for (int ni = 0; ni < 2; ++ni) {
        int c = cl0 + wc * 32 + ci * 16 + lg * 4;
        int n = n0 + wn * 32 + ni * 16 + lr;
        int hh = c >> 5, d = c & 31;
        int tt = n >> 5, k = n & 31;
        int s = ((k >> 2) & 1) * 16 + (k >> 3) * 4 + (k & 3);
        *(short4v*)(khp + (((size_t)hh * 128 + tt) * 32 + s) * 32 + d) = pack4(acc[ci][ni]);
      }
  } else {
    // v: vblk[h][tile][d][k]
    const int cv0 = (bx - 8) * 64;
    #pragma unroll
    for (int ci = 0; ci < 2; ++ci)
      #pragma unroll
      for (int ni = 0; ni < 2; ++ni) {
        int c = cv0 + wc * 32 + ci * 16 + lr;
        int n = n0 + wn * 32 + ni * 16 + lg * 4;
        int hh = c >> 5, d = c & 31;
        int tt = n >> 5, k = n & 31;
        *(short4v*)(vblk + (((size_t)hh * 128 + tt) * 32 + d) * 32 + k) = pack4(acc[ci][ni]);
      }
  }
}

// ---------------- attn11: de-clustered blocks + L-via-ones-MFMA ----------------
// block = (32-query tile, head), bid mapping SPREADS segments across XCDs/CUs
// (balance > locality). 4 waves split keys. L computed by mfma(P, ones) on the
// MFMA pipe -> no VALU adds, no epilogue shuffles.
__global__ __launch_bounds__(256) void attn11(
    const short* __restrict__ qb, const short* __restrict__ khp,
    const short* __restrict__ vblk, const int* __restrict__ cu,
    short* __restrict__ featb)
{
  __shared__ float red[4][64][24];
  const int tid = threadIdx.x;
  const int w = tid >> 6, l = tid & 63, lg = l >> 4, lr = l & 15;
  const int bid = blockIdx.x;               // 1024 blocks
  const int h = bid >> 7, t32 = bid & 127;  // consecutive bids = consecutive t
  const int n0 = t32 * 32;

  int cs[9];
  #pragma unroll
  for (int i = 0; i < 9; ++i) cs[i] = cu[i];

  const int qn0 = n0 + lr, qn1 = n0 + 16 + lr;
  int g0 = 0, g1 = 0, sg0 = 0, sgL = 0;
  #pragma unroll
  for (int j = 1; j <= 8; ++j) {
    g0  += (cs[j] <= qn0);
    g1  += (cs[j] <= qn1);
    sg0 += (cs[j] <= n0);
    sgL += (cs[j] <= n0 + 31);
  }
  const int kbeg0 = cs[g0], kend0 = cs[g0 + 1];
  const int kbeg1 = cs[g1], kend1 = cs[g1 + 1];
  const bool oneSeg = (sg0 == sgL);
  const int kbB = cs[sg0], keB = cs[sgL + 1];
  const int lo = kbB & ~31;
  const int hi = keB;
  const int t0 = lo >> 5;
  const int nT = (hi - lo + 31) >> 5;
  const int qT = (nT + 3) >> 2;
  const int it0 = w * qT;
  const int it1 = (it0 + qT < nT) ? (it0 + qT) : nT;

  const bf16x8 qf0 = *(const bf16x8*)(qb + (size_t)qn0 * 256 + h * 32 + lg * 8);
  const bf16x8 qf1 = *(const bf16x8*)(qb + (size_t)qn1 * 256 + h * 32 + lg * 8);
  const short* kL = khp  + (size_t)h * 131072 + lr * 32 + lg * 8;
  const short* vL = vblk + (size_t)h * 131072 + lr * 32 + lg * 8;

  f32x4 acc00 = {0.f,0.f,0.f,0.f}, acc01 = {0.f,0.f,0.f,0.f};
  f32x4 acc10 = {0.f,0.f,0.f,0.f}, acc11 = {0.f,0.f,0.f,0.f};
  f32x4 accL0 = {0.f,0.f,0.f,0.f}, accL1 = {0.f,0.f,0.f,0.f};
  const f32x4 z4 = {0.f, 0.f, 0.f, 0.f};
  bf16x8 ones;
  #pragma unroll
  for (int j = 0; j < 8; ++j) ones[j] = (short)0x3F80;   // bf16 1.0

  if (it0 < it1) {
    const short* kp = kL + (size_t)(t0 + it0) * 1024;
    const short* vp = vL + (size_t)(t0 + it0) * 1024;
    bf16x8 ka = *(const bf16x8*)(kp);
    bf16x8 kc = *(const bf16x8*)(kp + 512);
    bf16x8 va = *(const bf16x8*)(vp);
    bf16x8 vb = *(const bf16x8*)(vp + 512);
    for (int it = it0; it < it1; ++it) {
      const int itn = (it + 1 < it1) ? (it + 1) : it;
      const short* kpn = kL + (size_t)(t0 + itn) * 1024;
      const short* vpn = vL + (size_t)(t0 + itn) * 1024;
      bf16x8 kna = *(const bf16x8*)(kpn);
      bf16x8 knc = *(const bf16x8*)(kpn + 512);
      bf16x8 vna = *(const bf16x8*)(vpn);
      bf16x8 vnb = *(const bf16x8*)(vpn + 512);

      f32x4 s00 = __builtin_amdgcn_mfma_f32_16x16x32_bf16(ka, qf0, z4, 0, 0, 0);
      f32x4 s01 = __builtin_amdgcn_mfma_f32_16x16x32_bf16(kc, qf0, z4, 0, 0, 0);
      f32x4 s10 = __builtin_amdgcn_mfma_f32_16x16x32_bf16(ka, qf1, z4, 0, 0, 0);
      f32x4 s11 = __builtin_amdgcn_mfma_f32_16x16x32_bf16(kc, qf1, z4, 0, 0, 0);

      const int kt0 = (t0 + it) * 32;
      bf16x8 pf0, pf1;
      if (oneSeg & (kt0 >= kbB) & (kt0 + 32 <= keB)) {
        #pragma unroll
        for (int r = 0; r < 4; ++r) {
          pf0[r]     = f2b(exp2f(s00[r]));
          pf0[4 + r] = f2b(exp2f(s01[r]));
          pf1[r]     = f2b(exp2f(s10[r]));
          pf1[4 + r] = f2b(exp2f(s11[r]));
        }
      } else {
        const int kgb = kt0 + lg * 8;
        #pragma unroll
        for (int r = 0; r < 4; ++r) {
          int k0 = kgb + r, k1 = kgb + 4 + r;
          bool a00 = (k0 >= kbeg0) & (k0 < kend0);
          bool a01 = (k1 >= kbeg0) & (k1 < kend0);
          bool a10 = (k0 >= kbeg1) & (k0 < kend1);
          bool a11 = (k1 >= kbeg1) & (k1 < kend1);
          pf0[r]     = f2b(a00 ? exp2f(s00[r]) : 0.f);
          pf0[4 + r] = f2b(a01 ? exp2f(s01[r]) : 0.f);
          pf1[r]     = f2b(a10 ? exp2f(s10[r]) : 0.f);
          pf1[4 + r] = f2b(a11 ? exp2f(s11[r]) : 0.f);
        }
      }
      acc00 = __builtin_amdgcn_mfma_f32_16x16x32_bf16(pf0, va, acc00, 0, 0, 0);
      acc01 = __builtin_amdgcn_mfma_f32_16x16x32_bf16(pf0, vb, acc01, 0, 0, 0);
      acc10 = __builtin_amdgcn_mfma_f32_16x16x32_bf16(pf1, va, acc10, 0, 0, 0);
      acc11 = __builtin_amdgcn_mfma_f32_16x16x32_bf16(pf1, vb, acc11, 0, 0, 0);
      accL0 = __builtin_amdgcn_mfma_f32_16x16x32_bf16(pf0, ones, accL0, 0, 0, 0);
      accL1 = __builtin_amdgcn_mfma_f32_16x16x32_bf16(pf1, ones, accL1, 0, 0, 0);

      ka = kna; kc = knc; va = vna; vb = vnb;
    }
  }

  // merge the 4 key-splits: pure sum (fixed-max softmax). accL layout matches
  // acc layout (q = lg*4 + r), so no shuffles are needed.
  #pragma unroll
  for (int r = 0; r < 4; ++r) {
    red[w][l][r]      = acc00[r];
    red[w][l][4 + r]  = acc01[r];
    red[w][l][8 + r]  = acc10[r];
    red[w][l][12 + r] = acc11[r];
    red[w][l][16 + r] = accL0[r];
    red[w][l][20 + r] = accL1[r];
  }
  __syncthreads();
  if (w == 0) {
    float a00[4] = {0,0,0,0}, a01[4] = {0,0,0,0};
    float a10[4] = {0,0,0,0}, a11[4] = {0,0,0,0};
    float aL0[4] = {0,0,0,0}, aL1[4] = {0,0,0,0};
    #pragma unroll
    for (int wv = 0; wv < 4; ++wv) {
      #pragma unroll
      for (int r = 0; r < 4; ++r) {
        a00[r] += red[wv][l][r];      a01[r] += red[wv][l][4 + r];
        a10[r] += red[wv][l][8 + r];  a11[r] += red[wv][l][12 + r];
        aL0[r] += red[wv][l][16 + r]; aL1[r] += red[wv][l][20 + r];
      }
    }
    #pragma unroll
    for (int r = 0; r < 4; ++r) {
      float i0 = 1.f / aL0[r];
      float i1 = 1.f / aL1[r];
      int na = n0 + lg * 4 + r;
      int nb = n0 + 16 + lg * 4 + r;
      featb[(size_t)na * 256 + h * 32 + lr]      = f2b(a00[r] * i0);
      featb[(size_t)na * 256 + h * 32 + 16 + lr] = f2b(a01[r] * i0);
      featb[(size_t)nb * 256 + h * 32 + lr]      = f2b(a10[r] * i1);
      featb[(size_t)nb * 256 + h * 32 + 16 + lr] = f2b(a11[r] * i1);
    }
  }
}

// ---------------- output projection (MFMA, 64x64 tiles, swapped) + bias ----------------
__global__ __launch_bounds__(256) void gemm_out(
    const short* __restrict__ Fb, const short* __restrict__ WpT,
    const float* __restrict__ bias, float* __restrict__ out)
{
  __shared__ short Al[64][40];
  __shared__ short Wl[64][40];
  const int c0 = blockIdx.x * 64;
  const int n0 = blockIdx.y * 64;
  const int tid = threadIdx.x;
  const int w = tid >> 6, l = tid & 63, lg = l >> 4, lr = l & 15;
  const int wc = w & 1, wn = w >> 1;

  f32x4 acc[2][2];
  #pragma unroll
  for (int i = 0; i < 2; ++i)
    #pragma unroll
    for (int j = 0; j < 2; ++j) acc[i][j] = (f32x4){0.f, 0.f, 0.f, 0.f};

  for (int kt = 0; kt < 256; kt += 32) {
    __syncthreads();
    {
      int row = tid >> 2, seg = tid & 3;
      *(bf16x8*)&Al[row][seg * 8] = *(const bf16x8*)(Fb  + (size_t)(n0 + row) * 256 + kt + seg * 8);
      *(bf16x8*)&Wl[row][seg * 8] = *(const bf16x8*)(WpT + (size_t)(c0 + row) * 256 + kt + seg * 8);
    }
    __syncthreads();
    bf16x8 wf[2], xf[2];
    #pragma unroll
    for (int ci = 0; ci < 2; ++ci) wf[ci] = *(bf16x8*)&Wl[wc * 32 + ci * 16 + lr][lg * 8];
    #pragma unroll
    for (int ni = 0; ni < 2; ++ni) xf[ni] = *(bf16x8*)&Al[wn * 32 + ni * 16 + lr][lg * 8];
    #pragma unroll
    for (int ci = 0; ci < 2; ++ci)
      #pragma unroll
      for (int ni = 0; ni < 2; ++ni)
        acc[ci][ni] = __builtin_amdgcn_mfma_f32_16x16x32_bf16(wf[ci], xf[ni], acc[ci][ni], 0, 0, 0);
  }

  #pragma unroll
  for (int ci = 0; ci < 2; ++ci)
    #pragma unroll
    for (int ni = 0; ni < 2; ++ni) {
      int c = c0 + wc * 32 + ci * 16 + lg * 4;
      int n = n0 + wn * 32 + ni * 16 + lr;
      f32x4 bv = *(const f32x4*)(bias + c);
      f32x4 o = acc[ci][ni] + bv;
      *(f32x4*)(out + (size_t)n * 256 + c) = o;
    }
}

extern "C" void kernel_launch(void* const* d_in, const int* in_sizes, int n_in,
                              void* d_out, int out_size, void* d_ws, size_t ws_size,
                              hipStream_t stream) {
  (void)in_sizes; (void)n_in; (void)out_size; (void)ws_size;
  const float* qkv   = (const float*)d_in[0];
  const float* q_pos = (const float*)d_in[1];
  const int*   cu    = (const int*)d_in[2];
  const float* Wq    = (const float*)d_in[4];
  const float* Wkv   = (const float*)d_in[5];
  const float* Wproj = (const float*)d_in[6];
  const float* bproj = (const float*)d_in[7];
  float* out = (float*)d_out;

  const size_t M = (size_t)NTOK * CDIM;   // 1048576
  short* S    = (short*)d_ws;
  short* Xq   = S;
  short* X    = S + M;
  short* qb   = S + 2 * M;
  short* khp  = S + 3 * M;
  short* vblk = S + 4 * M;
  short* Fb   = S + 5 * M;
  short* WT   = S + 6 * M;
  short* WpT  = WT + 768 * 256;

  prep_kernel<<<1280, 256, 0, stream>>>(qkv, q_pos, Wq, Wkv, Wproj, Xq, X, WT, WpT);
  gemm_qkv<<<dim3(12, 64), 256, 0, stream>>>(Xq, X, WT, qb, khp, vblk);
  attn11<<<1024, 256, 0, stream>>>(qb, khp, vblk, cu, Fb);
  gemm_out<<<dim3(4, 64), 256, 0, stream>>>(Fb, WpT, bproj, out);
}

// Round 14
// 42.263 us; speedup vs baseline: 1.9871x; 1.2830x over previous
//
#include <hip/hip_runtime.h>
#include <hip/hip_bf16.h>
#include <math.h>

#define NTOK 4096
#define CDIM 256
#define NH   8
#define HD   32
// 32^-0.5 * log2(e): QK^T scale with exp->exp2 fold
#define QSCALE 0.2550565445517151f

typedef __attribute__((ext_vector_type(8))) short bf16x8;
typedef __attribute__((ext_vector_type(4))) short short4v;
typedef __attribute__((ext_vector_type(4))) float f32x4;

__device__ inline short f2b(float f) {
  union { __hip_bfloat16 h; short s; } u;
  u.h = __float2bfloat16(f);
  return u.s;
}
__device__ inline short4v pack4(f32x4 v) {
  short4v o; o[0] = f2b(v[0]); o[1] = f2b(v[1]); o[2] = f2b(v[2]); o[3] = f2b(v[3]);
  return o;
}

// ---------------- prep: bf16 conversions + weight transposes ----------------
__global__ __launch_bounds__(256) void prep_kernel(
    const float* __restrict__ qkv, const float* __restrict__ qpos,
    const float* __restrict__ Wq, const float* __restrict__ Wkv,
    const float* __restrict__ Wp,
    short* __restrict__ Xq, short* __restrict__ X,
    short* __restrict__ WT, short* __restrict__ WpT)
{
  const int b = blockIdx.x, t = threadIdx.x;
  if (b < 1024) {
    const int i4 = (b * 256 + t) * 4;
    float4 a = *(const float4*)(qkv + i4);
    float4 p = *(const float4*)(qpos + i4);
    short4v xo, qo;
    xo[0] = f2b(a.x); xo[1] = f2b(a.y); xo[2] = f2b(a.z); xo[3] = f2b(a.w);
    qo[0] = f2b(a.x + p.x); qo[1] = f2b(a.y + p.y); qo[2] = f2b(a.z + p.z); qo[3] = f2b(a.w + p.w);
    *(short4v*)(X + i4)  = xo;
    *(short4v*)(Xq + i4) = qo;
  } else {
    const int gid = (b - 1024) * 256 + t;   // 0..65535
    const int c  = gid & 1023;
    const int k4 = (gid >> 10) * 4;
    short4v o;
    if (c < 768) {
      #pragma unroll
      for (int j = 0; j < 4; ++j) {
        int k = k4 + j;
        float v = (c < 256) ? Wq[(size_t)k * 256 + c] * QSCALE
                            : Wkv[(size_t)k * 512 + (c - 256)];
        o[j] = f2b(v);
      }
      *(short4v*)(WT + (size_t)c * 256 + k4) = o;
    } else {
      const int cc = c - 768;
      #pragma unroll
      for (int j = 0; j < 4; ++j) o[j] = f2b(Wp[(size_t)(k4 + j) * 256 + cc]);
      *(short4v*)(WpT + (size_t)cc * 256 + k4) = o;
    }
  }
}

// ---------------- fused QKV projection (MFMA, 64x64 tiles) ----------------
// bx 0..3: q -> qb[n][c] (swapped); bx 4..7: k -> khp[h][tile][slot][d]
// (per-tile key-permuted); bx 8..11: v -> vblk[h][tile][d][k] (tile-blocked)
__global__ __launch_bounds__(256) void gemm_qkv(
    const short* __restrict__ Xq, const short* __restrict__ X,
    const short* __restrict__ WT,
    short* __restrict__ qb, short* __restrict__ khp, short* __restrict__ vblk)
{
  __shared__ short Al[64][40];
  __shared__ short Wl[64][40];
  const int bx = blockIdx.x;
  const int n0 = blockIdx.y * 64;
  const int c0 = bx * 64;                   // row range in WT [0,768)
  const int tid = threadIdx.x;
  const int w = tid >> 6, l = tid & 63, lg = l >> 4, lr = l & 15;
  const int wc = w & 1, wn = w >> 1;
  const short* A = (bx < 4) ? Xq : X;

  f32x4 acc[2][2];
  #pragma unroll
  for (int i = 0; i < 2; ++i)
    #pragma unroll
    for (int j = 0; j < 2; ++j) acc[i][j] = (f32x4){0.f, 0.f, 0.f, 0.f};

  for (int kt = 0; kt < 256; kt += 32) {
    __syncthreads();
    {
      int row = tid >> 2, seg = tid & 3;
      *(bf16x8*)&Al[row][seg * 8] = *(const bf16x8*)(A  + (size_t)(n0 + row) * 256 + kt + seg * 8);
      *(bf16x8*)&Wl[row][seg * 8] = *(const bf16x8*)(WT + (size_t)(c0 + row) * 256 + kt + seg * 8);
    }
    __syncthreads();
    bf16x8 wf[2], xf[2];
    #pragma unroll
    for (int ci = 0; ci < 2; ++ci) wf[ci] = *(bf16x8*)&Wl[wc * 32 + ci * 16 + lr][lg * 8];
    #pragma unroll
    for (int ni = 0; ni < 2; ++ni) xf[ni] = *(bf16x8*)&Al[wn * 32 + ni * 16 + lr][lg * 8];
    if (bx < 8) {
      #pragma unroll
      for (int ci = 0; ci < 2; ++ci)
        #pragma unroll
        for (int ni = 0; ni < 2; ++ni)
          acc[ci][ni] = __builtin_amdgcn_mfma_f32_16x16x32_bf16(wf[ci], xf[ni], acc[ci][ni], 0, 0, 0);
    } else {
      #pragma unroll
      for (int ci = 0; ci < 2; ++ci)
        #pragma unroll
        for (int ni = 0; ni < 2; ++ni)
          acc[ci][ni] = __builtin_amdgcn_mfma_f32_16x16x32_bf16(xf[ni], wf[ci], acc[ci][ni], 0, 0, 0);
    }
  }

  if (bx < 4) {
    const int cl0 = bx * 64;
    #pragma unroll
    for (int ci = 0; ci < 2; ++ci)
      #pragma unroll
      for (int ni = 0; ni < 2; ++ni) {
        int c = cl0 + wc * 32 + ci * 16 + lg * 4;
        int n = n0 + wn * 32 + ni * 16 + lr;
        *(short4v*)(qb + (size_t)n * 256 + c) = pack4(acc[ci][ni]);
      }
  } else if (bx < 8) {
    // k: khp[h][tile][slot][d], slot = ((k>>2)&1)*16 + (k>>3)*4 + (k&3)
    const int cl0 = (bx - 4) * 64;
    #pragma unroll
    for (int ci = 0; ci < 2; ++ci)
      #pragma unroll
      for (int ni = 0; ni < 2; ++ni) {
        int c = cl0 + wc * 32 + ci * 16 + lg * 4;
        int n = n0 + wn * 32 + ni * 16 + lr;
        int hh = c >> 5, d = c & 31;
        int tt = n >> 5, k = n & 31;
        int s = ((k >> 2) & 1) * 16 + (k >> 3) * 4 + (k & 3);
        *(short4v*)(khp + (((size_t)hh * 128 + tt) * 32 + s) * 32 + d) = pack4(acc[ci][ni]);
      }
  } else {
    // v: vblk[h][tile][d][k]
    const int cv0 = (bx - 8) * 64;
    #pragma unroll
    for (int ci = 0; ci < 2; ++ci)
      #pragma unroll
      for (int ni = 0; ni < 2; ++ni) {
        int c = cv0 + wc * 32 + ci * 16 + lr;
        int n = n0 + wn * 32 + ni * 16 + lg * 4;
        int hh = c >> 5, d = c & 31;
        int tt = n >> 5, k = n & 31;
        *(short4v*)(vblk + (((size_t)hh * 128 + tt) * 32 + d) * 32 + k) = pack4(acc[ci][ni]);
      }
  }
}

// ---------------- attn12: r9 structure + exp2-fold + L-via-ones-MFMA ----------------
// block = (32-query tile, head) via r9's CLUSTERED XCD swizzle (locality wins).
// 4 waves split keys in 32-key tiles, 1-deep prefetch, interior fast path.
__global__ __launch_bounds__(256) void attn12(
    const short* __restrict__ qb, const short* __restrict__ khp,
    const short* __restrict__ vblk, const int* __restrict__ cu,
    short* __restrict__ featb)
{
  __shared__ float red[4][64][24];
  const int tid = threadIdx.x;
  const int w = tid >> 6, l = tid & 63, lg = l >> 4, lr = l & 15;
  const int bid = blockIdx.x;                       // 1024 blocks (8 | 1024)
  const int lid = ((bid & 7) << 7) | (bid >> 3);    // clustered XCD swizzle (r9)
  const int h = lid & 7, t32 = lid >> 3;
  const int n0 = t32 * 32;

  int cs[9];
  #pragma unroll
  for (int i = 0; i < 9; ++i) cs[i] = cu[i];

  const int qn0 = n0 + lr, qn1 = n0 + 16 + lr;
  int g0 = 0, g1 = 0, sg0 = 0, sgL = 0;
  #pragma unroll
  for (int j = 1; j <= 8; ++j) {
    g0  += (cs[j] <= qn0);
    g1  += (cs[j] <= qn1);
    sg0 += (cs[j] <= n0);
    sgL += (cs[j] <= n0 + 31);
  }
  const int kbeg0 = cs[g0], kend0 = cs[g0 + 1];
  const int kbeg1 = cs[g1], kend1 = cs[g1 + 1];
  const bool oneSeg = (sg0 == sgL);
  const int kbB = cs[sg0], keB = cs[sgL + 1];
  const int lo = kbB & ~31;
  const int hi = keB;
  const int t0 = lo >> 5;
  const int nT = (hi - lo + 31) >> 5;
  const int qT = (nT + 3) >> 2;
  const int it0 = w * qT;
  const int it1 = (it0 + qT < nT) ? (it0 + qT) : nT;

  const bf16x8 qf0 = *(const bf16x8*)(qb + (size_t)qn0 * 256 + h * 32 + lg * 8);
  const bf16x8 qf1 = *(const bf16x8*)(qb + (size_t)qn1 * 256 + h * 32 + lg * 8);
  const short* kL = khp  + (size_t)h * 131072 + lr * 32 + lg * 8;
  const short* vL = vblk + (size_t)h * 131072 + lr * 32 + lg * 8;

  f32x4 acc00 = {0.f,0.f,0.f,0.f}, acc01 = {0.f,0.f,0.f,0.f};
  f32x4 acc10 = {0.f,0.f,0.f,0.f}, acc11 = {0.f,0.f,0.f,0.f};
  f32x4 accL0 = {0.f,0.f,0.f,0.f}, accL1 = {0.f,0.f,0.f,0.f};
  const f32x4 z4 = {0.f, 0.f, 0.f, 0.f};
  bf16x8 ones;
  #pragma unroll
  for (int j = 0; j < 8; ++j) ones[j] = (short)0x3F80;   // bf16 1.0

  if (it0 < it1) {
    const short* kp = kL + (size_t)(t0 + it0) * 1024;
    const short* vp = vL + (size_t)(t0 + it0) * 1024;
    bf16x8 ka = *(const bf16x8*)(kp);
    bf16x8 kc = *(const bf16x8*)(kp + 512);
    bf16x8 va = *(const bf16x8*)(vp);
    bf16x8 vb = *(const bf16x8*)(vp + 512);
    for (int it = it0; it < it1; ++it) {
      const int itn = (it + 1 < it1) ? (it + 1) : it;
      const short* kpn = kL + (size_t)(t0 + itn) * 1024;
      const short* vpn = vL + (size_t)(t0 + itn) * 1024;
      bf16x8 kna = *(const bf16x8*)(kpn);
      bf16x8 knc = *(const bf16x8*)(kpn + 512);
      bf16x8 vna = *(const bf16x8*)(vpn);
      bf16x8 vnb = *(const bf16x8*)(vpn + 512);

      f32x4 s00 = __builtin_amdgcn_mfma_f32_16x16x32_bf16(ka, qf0, z4, 0, 0, 0);
      f32x4 s01 = __builtin_amdgcn_mfma_f32_16x16x32_bf16(kc, qf0, z4, 0, 0, 0);
      f32x4 s10 = __builtin_amdgcn_mfma_f32_16x16x32_bf16(ka, qf1, z4, 0, 0, 0);
      f32x4 s11 = __builtin_amdgcn_mfma_f32_16x16x32_bf16(kc, qf1, z4, 0, 0, 0);

      const int kt0 = (t0 + it) * 32;
      bf16x8 pf0, pf1;
      if (oneSeg & (kt0 >= kbB) & (kt0 + 32 <= keB)) {
        // interior tile: no masking
        #pragma unroll
        for (int r = 0; r < 4; ++r) {
          pf0[r]     = f2b(exp2f(s00[r]));
          pf0[4 + r] = f2b(exp2f(s01[r]));
          pf1[r]     = f2b(exp2f(s10[r]));
          pf1[4 + r] = f2b(exp2f(s11[r]));
        }
      } else {
        const int kgb = kt0 + lg * 8;
        #pragma unroll
        for (int r = 0; r < 4; ++r) {
          int k0 = kgb + r, k1 = kgb + 4 + r;
          bool a00 = (k0 >= kbeg0) & (k0 < kend0);
          bool a01 = (k1 >= kbeg0) & (k1 < kend0);
          bool a10 = (k0 >= kbeg1) & (k0 < kend1);
          bool a11 = (k1 >= kbeg1) & (k1 < kend1);
          pf0[r]     = f2b(a00 ? exp2f(s00[r]) : 0.f);
          pf0[4 + r] = f2b(a01 ? exp2f(s01[r]) : 0.f);
          pf1[r]     = f2b(a10 ? exp2f(s10[r]) : 0.f);
          pf1[4 + r] = f2b(a11 ? exp2f(s11[r]) : 0.f);
        }
      }
      acc00 = __builtin_amdgcn_mfma_f32_16x16x32_bf16(pf0, va, acc00, 0, 0, 0);
      acc01 = __builtin_amdgcn_mfma_f32_16x16x32_bf16(pf0, vb, acc01, 0, 0, 0);
      acc10 = __builtin_amdgcn_mfma_f32_16x16x32_bf16(pf1, va, acc10, 0, 0, 0);
      acc11 = __builtin_amdgcn_mfma_f32_16x16x32_bf16(pf1, vb, acc11, 0, 0, 0);
      accL0 = __builtin_amdgcn_mfma_f32_16x16x32_bf16(pf0, ones, accL0, 0, 0, 0);
      accL1 = __builtin_amdgcn_mfma_f32_16x16x32_bf16(pf1, ones, accL1, 0, 0, 0);

      ka = kna; kc = knc; va = vna; vb = vnb;
    }
  }

  // merge the 4 key-splits: pure sum (fixed-max softmax). accL layout matches
  // acc layout (q = lg*4 + r) -> no shuffles needed.
  #pragma unroll
  for (int r = 0; r < 4; ++r) {
    red[w][l][r]      = acc00[r];
    red[w][l][4 + r]  = acc01[r];
    red[w][l][8 + r]  = acc10[r];
    red[w][l][12 + r] = acc11[r];
    red[w][l][16 + r] = accL0[r];
    red[w][l][20 + r] = accL1[r];
  }
  __syncthreads();
  if (w == 0) {
    float a00[4] = {0,0,0,0}, a01[4] = {0,0,0,0};
    float a10[4] = {0,0,0,0}, a11[4] = {0,0,0,0};
    float aL0[4] = {0,0,0,0}, aL1[4] = {0,0,0,0};
    #pragma unroll
    for (int wv = 0; wv < 4; ++wv) {
      #pragma unroll
      for (int r = 0; r < 4; ++r) {
        a00[r] += red[wv][l][r];      a01[r] += red[wv][l][4 + r];
        a10[r] += red[wv][l][8 + r];  a11[r] += red[wv][l][12 + r];
        aL0[r] += red[wv][l][16 + r]; aL1[r] += red[wv][l][20 + r];
      }
    }
    #pragma unroll
    for (int r = 0; r < 4; ++r) {
      float i0 = 1.f / aL0[r];
      float i1 = 1.f / aL1[r];
      int na = n0 + lg * 4 + r;
      int nb = n0 + 16 + lg * 4 + r;
      featb[(size_t)na * 256 + h * 32 + lr]      = f2b(a00[r] * i0);
      featb[(size_t)na * 256 + h * 32 + 16 + lr] = f2b(a01[r] * i0);
      featb[(size_t)nb * 256 + h * 32 + lr]      = f2b(a10[r] * i1);
      featb[(size_t)nb * 256 + h * 32 + 16 + lr] = f2b(a11[r] * i1);
    }
  }
}

// ---------------- output projection (MFMA, 64x64 tiles, swapped) + bias ----------------
__global__ __launch_bounds__(256) void gemm_out(
    const short* __restrict__ Fb, const short* __restrict__ WpT,
    const float* __restrict__ bias, float* __restrict__ out)
{
  __shared__ short Al[64][40];
  __shared__ short Wl[64][40];
  const int c0 = blockIdx.x * 64;
  const int n0 = blockIdx.y * 64;
  const int tid = threadIdx.x;
  const int w = tid >> 6, l = tid & 63, lg = l >> 4, lr = l & 15;
  const int wc = w & 1, wn = w >> 1;

  f32x4 acc[2][2];
  #pragma unroll
  for (int i = 0; i < 2; ++i)
    #pragma unroll
    for (int j = 0; j < 2; ++j) acc[i][j] = (f32x4){0.f, 0.f, 0.f, 0.f};

  for (int kt = 0; kt < 256; kt += 32) {
    __syncthreads();
    {
      int row = tid >> 2, seg = tid & 3;
      *(bf16x8*)&Al[row][seg * 8] = *(const bf16x8*)(Fb  + (size_t)(n0 + row) * 256 + kt + seg * 8);
      *(bf16x8*)&Wl[row][seg * 8] = *(const bf16x8*)(WpT + (size_t)(c0 + row) * 256 + kt + seg * 8);
    }
    __syncthreads();
    bf16x8 wf[2], xf[2];
    #pragma unroll
    for (int ci = 0; ci < 2; ++ci) wf[ci] = *(bf16x8*)&Wl[wc * 32 + ci * 16 + lr][lg * 8];
    #pragma unroll
    for (int ni = 0; ni < 2; ++ni) xf[ni] = *(bf16x8*)&Al[wn * 32 + ni * 16 + lr][lg * 8];
    #pragma unroll
    for (int ci = 0; ci < 2; ++ci)
      #pragma unroll
      for (int ni = 0; ni < 2; ++ni)
        acc[ci][ni] = __builtin_amdgcn_mfma_f32_16x16x32_bf16(wf[ci], xf[ni], acc[ci][ni], 0, 0, 0);
  }

  #pragma unroll
  for (int ci = 0; ci < 2; ++ci)
    #pragma unroll
    for (int ni = 0; ni < 2; ++ni) {
      int c = c0 + wc * 32 + ci * 16 + lg * 4;
      int n = n0 + wn * 32 + ni * 16 + lr;
      f32x4 bv = *(const f32x4*)(bias + c);
      f32x4 o = acc[ci][ni] + bv;
      *(f32x4*)(out + (size_t)n * 256 + c) = o;
    }
}

extern "C" void kernel_launch(void* const* d_in, const int* in_sizes, int n_in,
                              void* d_out, int out_size, void* d_ws, size_t ws_size,
                              hipStream_t stream) {
  (void)in_sizes; (void)n_in; (void)out_size; (void)ws_size;
  const float* qkv   = (const float*)d_in[0];
  const float* q_pos = (const float*)d_in[1];
  const int*   cu    = (const int*)d_in[2];
  const float* Wq    = (const float*)d_in[4];
  const float* Wkv   = (const float*)d_in[5];
  const float* Wproj = (const float*)d_in[6];
  const float* bproj = (const float*)d_in[7];
  float* out = (float*)d_out;

  const size_t M = (size_t)NTOK * CDIM;   // 1048576
  short* S    = (short*)d_ws;
  short* Xq   = S;
  short* X    = S + M;
  short* qb   = S + 2 * M;
  short* khp  = S + 3 * M;
  short* vblk = S + 4 * M;
  short* Fb   = S + 5 * M;
  short* WT   = S + 6 * M;
  short* WpT  = WT + 768 * 256;

  prep_kernel<<<1280, 256, 0, stream>>>(qkv, q_pos, Wq, Wkv, Wproj, Xq, X, WT, WpT);
  gemm_qkv<<<dim3(12, 64), 256, 0, stream>>>(Xq, X, WT, qb, khp, vblk);
  attn12<<<1024, 256, 0, stream>>>(qb, khp, vblk, cu, Fb);
  gemm_out<<<dim3(4, 64), 256, 0, stream>>>(Fb, WpT, bproj, out);
}

// Round 15
// 38.558 us; speedup vs baseline: 2.1781x; 1.0961x over previous
//
#include <hip/hip_runtime.h>
#include <hip/hip_bf16.h>
#include <math.h>

#define NTOK 4096
#define CDIM 256
#define NH   8
#define HD   32
#define SCALE 0.17677669529663687f  // 32^-0.5

typedef __attribute__((ext_vector_type(8))) short bf16x8;
typedef __attribute__((ext_vector_type(4))) short short4v;
typedef __attribute__((ext_vector_type(4))) float f32x4;

__device__ inline short f2b(float f) {
  union { __hip_bfloat16 h; short s; } u;
  u.h = __float2bfloat16(f);
  return u.s;
}
__device__ inline short4v pack4(f32x4 v) {
  short4v o; o[0] = f2b(v[0]); o[1] = f2b(v[1]); o[2] = f2b(v[2]); o[3] = f2b(v[3]);
  return o;
}

// ---------------- prep: bf16 conversions + weight transposes ----------------
__global__ __launch_bounds__(256) void prep_kernel(
    const float* __restrict__ qkv, const float* __restrict__ qpos,
    const float* __restrict__ Wq, const float* __restrict__ Wkv,
    const float* __restrict__ Wp,
    short* __restrict__ Xq, short* __restrict__ X,
    short* __restrict__ WT, short* __restrict__ WpT)
{
  const int b = blockIdx.x, t = threadIdx.x;
  if (b < 1024) {
    const int i4 = (b * 256 + t) * 4;
    float4 a = *(const float4*)(qkv + i4);
    float4 p = *(const float4*)(qpos + i4);
    short4v xo, qo;
    xo[0] = f2b(a.x); xo[1] = f2b(a.y); xo[2] = f2b(a.z); xo[3] = f2b(a.w);
    qo[0] = f2b(a.x + p.x); qo[1] = f2b(a.y + p.y); qo[2] = f2b(a.z + p.z); qo[3] = f2b(a.w + p.w);
    *(short4v*)(X + i4)  = xo;
    *(short4v*)(Xq + i4) = qo;
  } else {
    const int gid = (b - 1024) * 256 + t;   // 0..65535
    const int c  = gid & 1023;
    const int k4 = (gid >> 10) * 4;
    short4v o;
    if (c < 768) {
      #pragma unroll
      for (int j = 0; j < 4; ++j) {
        int k = k4 + j;
        float v = (c < 256) ? Wq[(size_t)k * 256 + c] * SCALE
                            : Wkv[(size_t)k * 512 + (c - 256)];
        o[j] = f2b(v);
      }
      *(short4v*)(WT + (size_t)c * 256 + k4) = o;
    } else {
      const int cc = c - 768;
      #pragma unroll
      for (int j = 0; j < 4; ++j) o[j] = f2b(Wp[(size_t)(k4 + j) * 256 + cc]);
      *(short4v*)(WpT + (size_t)cc * 256 + k4) = o;
    }
  }
}

// ---------------- fused QKV projection (MFMA, 64x64 tiles) ----------------
// bx 0..3: q -> qb[n][c] (swapped); bx 4..7: k -> khp[h][tile][slot][d]
// (per-tile key-permuted); bx 8..11: v -> vblk[h][tile][d][k] (tile-blocked)
__global__ __launch_bounds__(256) void gemm_qkv(
    const short* __restrict__ Xq, const short* __restrict__ X,
    const short* __restrict__ WT,
    short* __restrict__ qb, short* __restrict__ khp, short* __restrict__ vblk)
{
  __shared__ short Al[64][40];
  __shared__ short Wl[64][40];
  const int bx = blockIdx.x;
  const int n0 = blockIdx.y * 64;
  const int c0 = bx * 64;                   // row range in WT [0,768)
  const int tid = threadIdx.x;
  const int w = tid >> 6, l = tid & 63, lg = l >> 4, lr = l & 15;
  const int wc = w & 1, wn = w >> 1;
  const short* A = (bx < 4) ? Xq : X;

  f32x4 acc[2][2];
  #pragma unroll
  for (int i = 0; i < 2; ++i)
    #pragma unroll
    for (int j = 0; j < 2; ++j) acc[i][j] = (f32x4){0.f, 0.f, 0.f, 0.f};

  for (int kt = 0; kt < 256; kt += 32) {
    __syncthreads();
    {
      int row = tid >> 2, seg = tid & 3;
      *(bf16x8*)&Al[row][seg * 8] = *(const bf16x8*)(A  + (size_t)(n0 + row) * 256 + kt + seg * 8);
      *(bf16x8*)&Wl[row][seg * 8] = *(const bf16x8*)(WT + (size_t)(c0 + row) * 256 + kt + seg * 8);
    }
    __syncthreads();
    bf16x8 wf[2], xf[2];
    #pragma unroll
    for (int ci = 0; ci < 2; ++ci) wf[ci] = *(bf16x8*)&Wl[wc * 32 + ci * 16 + lr][lg * 8];
    #pragma unroll
    for (int ni = 0; ni < 2; ++ni) xf[ni] = *(bf16x8*)&Al[wn * 32 + ni * 16 + lr][lg * 8];
    if (bx < 8) {
      #pragma unroll
      for (int ci = 0; ci < 2; ++ci)
        #pragma unroll
        for (int ni = 0; ni < 2; ++ni)
          acc[ci][ni] = __builtin_amdgcn_mfma_f32_16x16x32_bf16(wf[ci], xf[ni], acc[ci][ni], 0, 0, 0);
    } else {
      #pragma unroll
      for (int ci = 0; ci < 2; ++ci)
        #pragma unroll
        for (int ni = 0; ni < 2; ++ni)
          acc[ci][ni] = __builtin_amdgcn_mfma_f32_16x16x32_bf16(xf[ni], wf[ci], acc[ci][ni], 0, 0, 0);
    }
  }

  if (bx < 4) {
    const int cl0 = bx * 64;
    #pragma unroll
    for (int ci = 0; ci < 2; ++ci)
      #pragma unroll
      for (int ni = 0; ni < 2; ++ni) {
        int c = cl0 + wc * 32 + ci * 16 + lg * 4;
        int n = n0 + wn * 32 + ni * 16 + lr;
        *(short4v*)(qb + (size_t)n * 256 + c) = pack4(acc[ci][ni]);
      }
  } else if (bx < 8) {
    // k: khp[h][tile][slot][d], slot = ((k>>2)&1)*16 + (k>>3)*4 + (k&3)
    const int cl0 = (bx - 4) * 64;
    #pragma unroll
    for (int ci = 0; ci < 2; ++ci)
      #pragma unroll
      for (int ni = 0; ni < 2; ++ni) {
        int c = cl0 + wc * 32 + ci * 16 + lg * 4;
        int n = n0 + wn * 32 + ni * 16 + lr;
        int hh = c >> 5, d = c & 31;
        int tt = n >> 5, k = n & 31;
        int s = ((k >> 2) & 1) * 16 + (k >> 3) * 4 + (k & 3);
        *(short4v*)(khp + (((size_t)hh * 128 + tt) * 32 + s) * 32 + d) = pack4(acc[ci][ni]);
      }
  } else {
    // v: vblk[h][tile][d][k]
    const int cv0 = (bx - 8) * 64;
    #pragma unroll
    for (int ci = 0; ci < 2; ++ci)
      #pragma unroll
      for (int ni = 0; ni < 2; ++ni) {
        int c = cv0 + wc * 32 + ci * 16 + lr;
        int n = n0 + wn * 32 + ni * 16 + lg * 4;
        int hh = c >> 5, d = c & 31;
        int tt = n >> 5, k = n & 31;
        *(short4v*)(vblk + (((size_t)hh * 128 + tt) * 32 + d) * 32 + k) = pack4(acc[ci][ni]);
      }
  }
}

// ---------------- attn13: r9 structure, IDENTITY block mapping ----------------
// h = bid&7 -> HW round-robin puts ONE HEAD per XCD (512 KB K/V, L2-resident);
// t32 = bid>>3 -> each CU gets t32 spread {c, c+32, c+64, c+96} -> segments
// balanced across CUs. Locality AND balance simultaneously.
__global__ __launch_bounds__(256) void attn13(
    const short* __restrict__ qb, const short* __restrict__ khp,
    const short* __restrict__ vblk, const int* __restrict__ cu,
    short* __restrict__ featb)
{
  __shared__ float red[4][64][18];
  const int tid = threadIdx.x;
  const int w = tid >> 6, l = tid & 63, lg = l >> 4, lr = l & 15;
  const int bid = blockIdx.x;               // 1024 blocks
  const int h = bid & 7, t32 = bid >> 3;    // identity mapping (see above)
  const int n0 = t32 * 32;

  int cs[9];
  #pragma unroll
  for (int i = 0; i < 9; ++i) cs[i] = cu[i];

  const int qn0 = n0 + lr, qn1 = n0 + 16 + lr;
  int g0 = 0, g1 = 0, sg0 = 0, sgL = 0;
  #pragma unroll
  for (int j = 1; j <= 8; ++j) {
    g0  += (cs[j] <= qn0);
    g1  += (cs[j] <= qn1);
    sg0 += (cs[j] <= n0);
    sgL += (cs[j] <= n0 + 31);
  }
  const int kbeg0 = cs[g0], kend0 = cs[g0 + 1];
  const int kbeg1 = cs[g1], kend1 = cs[g1 + 1];
  const bool oneSeg = (sg0 == sgL);
  const int kbB = cs[sg0], keB = cs[sgL + 1];
  const int lo = kbB & ~31;
  const int hi = keB;
  const int t0 = lo >> 5;
  const int nT = (hi - lo + 31) >> 5;
  const int qT = (nT + 3) >> 2;
  const int it0 = w * qT;
  const int it1 = (it0 + qT < nT) ? (it0 + qT) : nT;

  const bf16x8 qf0 = *(const bf16x8*)(qb + (size_t)qn0 * 256 + h * 32 + lg * 8);
  const bf16x8 qf1 = *(const bf16x8*)(qb + (size_t)qn1 * 256 + h * 32 + lg * 8);
  const short* kL = khp  + (size_t)h * 131072 + lr * 32 + lg * 8;
  const short* vL = vblk + (size_t)h * 131072 + lr * 32 + lg * 8;

  f32x4 acc00 = {0.f,0.f,0.f,0.f}, acc01 = {0.f,0.f,0.f,0.f};
  f32x4 acc10 = {0.f,0.f,0.f,0.f}, acc11 = {0.f,0.f,0.f,0.f};
  float Lp0 = 0.f, Lp1 = 0.f;
  const f32x4 z4 = {0.f, 0.f, 0.f, 0.f};

  if (it0 < it1) {
    const short* kp = kL + (size_t)(t0 + it0) * 1024;
    const short* vp = vL + (size_t)(t0 + it0) * 1024;
    bf16x8 ka = *(const bf16x8*)(kp);
    bf16x8 kc = *(const bf16x8*)(kp + 512);
    bf16x8 va = *(const bf16x8*)(vp);
    bf16x8 vb = *(const bf16x8*)(vp + 512);
    for (int it = it0; it < it1; ++it) {
      const int itn = (it + 1 < it1) ? (it + 1) : it;
      const short* kpn = kL + (size_t)(t0 + itn) * 1024;
      const short* vpn = vL + (size_t)(t0 + itn) * 1024;
      bf16x8 kna = *(const bf16x8*)(kpn);
      bf16x8 knc = *(const bf16x8*)(kpn + 512);
      bf16x8 vna = *(const bf16x8*)(vpn);
      bf16x8 vnb = *(const bf16x8*)(vpn + 512);

      f32x4 s00 = __builtin_amdgcn_mfma_f32_16x16x32_bf16(ka, qf0, z4, 0, 0, 0);
      f32x4 s01 = __builtin_amdgcn_mfma_f32_16x16x32_bf16(kc, qf0, z4, 0, 0, 0);
      f32x4 s10 = __builtin_amdgcn_mfma_f32_16x16x32_bf16(ka, qf1, z4, 0, 0, 0);
      f32x4 s11 = __builtin_amdgcn_mfma_f32_16x16x32_bf16(kc, qf1, z4, 0, 0, 0);

      const int kt0 = (t0 + it) * 32;
      bf16x8 pf0, pf1;
      if (oneSeg & (kt0 >= kbB) & (kt0 + 32 <= keB)) {
        // interior tile: no masking
        #pragma unroll
        for (int r = 0; r < 4; ++r) {
          float p00 = __expf(s00[r]), p01 = __expf(s01[r]);
          float p10 = __expf(s10[r]), p11 = __expf(s11[r]);
          Lp0 += p00 + p01; Lp1 += p10 + p11;
          pf0[r] = f2b(p00); pf0[4 + r] = f2b(p01);
          pf1[r] = f2b(p10); pf1[4 + r] = f2b(p11);
        }
      } else {
        const int kgb = kt0 + lg * 8;
        #pragma unroll
        for (int r = 0; r < 4; ++r) {
          int k0 = kgb + r, k1 = kgb + 4 + r;
          bool a00 = (k0 >= kbeg0) & (k0 < kend0);
          bool a01 = (k1 >= kbeg0) & (k1 < kend0);
          bool a10 = (k0 >= kbeg1) & (k0 < kend1);
          bool a11 = (k1 >= kbeg1) & (k1 < kend1);
          float p00 = a00 ? __expf(s00[r]) : 0.f;
          float p01 = a01 ? __expf(s01[r]) : 0.f;
          float p10 = a10 ? __expf(s10[r]) : 0.f;
          float p11 = a11 ? __expf(s11[r]) : 0.f;
          Lp0 += p00 + p01; Lp1 += p10 + p11;
          pf0[r] = f2b(p00); pf0[4 + r] = f2b(p01);
          pf1[r] = f2b(p10); pf1[4 + r] = f2b(p11);
        }
      }
      acc00 = __builtin_amdgcn_mfma_f32_16x16x32_bf16(pf0, va, acc00, 0, 0, 0);
      acc01 = __builtin_amdgcn_mfma_f32_16x16x32_bf16(pf0, vb, acc01, 0, 0, 0);
      acc10 = __builtin_amdgcn_mfma_f32_16x16x32_bf16(pf1, va, acc10, 0, 0, 0);
      acc11 = __builtin_amdgcn_mfma_f32_16x16x32_bf16(pf1, vb, acc11, 0, 0, 0);

      ka = kna; kc = knc; va = vna; vb = vnb;
    }
  }

  // merge the 4 key-splits: pure sum (fixed-max softmax)
  #pragma unroll
  for (int r = 0; r < 4; ++r) {
    red[w][l][r]      = acc00[r];
    red[w][l][4 + r]  = acc01[r];
    red[w][l][8 + r]  = acc10[r];
    red[w][l][12 + r] = acc11[r];
  }
  red[w][l][16] = Lp0;
  red[w][l][17] = Lp1;
  __syncthreads();
  if (w == 0) {
    float a00[4] = {0,0,0,0}, a01[4] = {0,0,0,0};
    float a10[4] = {0,0,0,0}, a11[4] = {0,0,0,0};
    float Ls0 = 0.f, Ls1 = 0.f;
    #pragma unroll
    for (int wv = 0; wv < 4; ++wv) {
      #pragma unroll
      for (int r = 0; r < 4; ++r) {
        a00[r] += red[wv][l][r];      a01[r] += red[wv][l][4 + r];
        a10[r] += red[wv][l][8 + r];  a11[r] += red[wv][l][12 + r];
      }
      Ls0 += red[wv][l][16];
      Ls1 += red[wv][l][17];
    }
    Ls0 += __shfl_xor(Ls0, 16); Ls0 += __shfl_xor(Ls0, 32);
    Ls1 += __shfl_xor(Ls1, 16); Ls1 += __shfl_xor(Ls1, 32);
    float inv0 = 1.f / Ls0, inv1 = 1.f / Ls1;
    #pragma unroll
    for (int r = 0; r < 4; ++r) {
      float i0 = __shfl(inv0, lg * 4 + r);
      float i1 = __shfl(inv1, lg * 4 + r);
      int na = n0 + lg * 4 + r;
      int nb = n0 + 16 + lg * 4 + r;
      featb[(size_t)na * 256 + h * 32 + lr]      = f2b(a00[r] * i0);
      featb[(size_t)na * 256 + h * 32 + 16 + lr] = f2b(a01[r] * i0);
      featb[(size_t)nb * 256 + h * 32 + lr]      = f2b(a10[r] * i1);
      featb[(size_t)nb * 256 + h * 32 + 16 + lr] = f2b(a11[r] * i1);
    }
  }
}

// ---------------- output projection (MFMA, 64x64 tiles, swapped) + bias ----------------
__global__ __launch_bounds__(256) void gemm_out(
    const short* __restrict__ Fb, const short* __restrict__ WpT,
    const float* __restrict__ bias, float* __restrict__ out)
{
  __shared__ short Al[64][40];
  __shared__ short Wl[64][40];
  const int c0 = blockIdx.x * 64;
  const int n0 = blockIdx.y * 64;
  const int tid = threadIdx.x;
  const int w = tid >> 6, l = tid & 63, lg = l >> 4, lr = l & 15;
  const int wc = w & 1, wn = w >> 1;

  f32x4 acc[2][2];
  #pragma unroll
  for (int i = 0; i < 2; ++i)
    #pragma unroll
    for (int j = 0; j < 2; ++j) acc[i][j] = (f32x4){0.f, 0.f, 0.f, 0.f};

  for (int kt = 0; kt < 256; kt += 32) {
    __syncthreads();
    {
      int row = tid >> 2, seg = tid & 3;
      *(bf16x8*)&Al[row][seg * 8] = *(const bf16x8*)(Fb  + (size_t)(n0 + row) * 256 + kt + seg * 8);
      *(bf16x8*)&Wl[row][seg * 8] = *(const bf16x8*)(WpT + (size_t)(c0 + row) * 256 + kt + seg * 8);
    }
    __syncthreads();
    bf16x8 wf[2], xf[2];
    #pragma unroll
    for (int ci = 0; ci < 2; ++ci) wf[ci] = *(bf16x8*)&Wl[wc * 32 + ci * 16 + lr][lg * 8];
    #pragma unroll
    for (int ni = 0; ni < 2; ++ni) xf[ni] = *(bf16x8*)&Al[wn * 32 + ni * 16 + lr][lg * 8];
    #pragma unroll
    for (int ci = 0; ci < 2; ++ci)
      #pragma unroll
      for (int ni = 0; ni < 2; ++ni)
        acc[ci][ni] = __builtin_amdgcn_mfma_f32_16x16x32_bf16(wf[ci], xf[ni], acc[ci][ni], 0, 0, 0);
  }

  #pragma unroll
  for (int ci = 0; ci < 2; ++ci)
    #pragma unroll
    for (int ni = 0; ni < 2; ++ni) {
      int c = c0 + wc * 32 + ci * 16 + lg * 4;
      int n = n0 + wn * 32 + ni * 16 + lr;
      f32x4 bv = *(const f32x4*)(bias + c);
      f32x4 o = acc[ci][ni] + bv;
      *(f32x4*)(out + (size_t)n * 256 + c) = o;
    }
}

extern "C" void kernel_launch(void* const* d_in, const int* in_sizes, int n_in,
                              void* d_out, int out_size, void* d_ws, size_t ws_size,
                              hipStream_t stream) {
  (void)in_sizes; (void)n_in; (void)out_size; (void)ws_size;
  const float* qkv   = (const float*)d_in[0];
  const float* q_pos = (const float*)d_in[1];
  const int*   cu    = (const int*)d_in[2];
  const float* Wq    = (const float*)d_in[4];
  const float* Wkv   = (const float*)d_in[5];
  const float* Wproj = (const float*)d_in[6];
  const float* bproj = (const float*)d_in[7];
  float* out = (float*)d_out;

  const size_t M = (size_t)NTOK * CDIM;   // 1048576
  short* S    = (short*)d_ws;
  short* Xq   = S;
  short* X    = S + M;
  short* qb   = S + 2 * M;
  short* khp  = S + 3 * M;
  short* vblk = S + 4 * M;
  short* Fb   = S + 5 * M;
  short* WT   = S + 6 * M;
  short* WpT  = WT + 768 * 256;

  prep_kernel<<<1280, 256, 0, stream>>>(qkv, q_pos, Wq, Wkv, Wproj, Xq, X, WT, WpT);
  gemm_qkv<<<dim3(12, 64), 256, 0, stream>>>(Xq, X, WT, qb, khp, vblk);
  attn13<<<1024, 256, 0, stream>>>(qb, khp, vblk, cu, Fb);
  gemm_out<<<dim3(4, 64), 256, 0, stream>>>(Fb, WpT, bproj, out);
}